// Round 14
// baseline (332.809 us; speedup 1.0000x reference)
//
#include <hip/hip_runtime.h>

// MultiHeadAttention: B=8, C=256, H=8, D=32, T=16, P=1024, F=D*T=512
//  k_wconv : W fp32 -> Wall[768][256] bf16 (chunk-swizzled by o&7)
//  k_xt    : x fp32 [b][c][n] -> Xbf [b][n][c] bf16 (chunk-swizzled by n&7)
//  k_proj2 : GEMM Wall x Xbf. K,Q -> fp8e4m3 x16 (interleaved layout); V -> bf16.
//  k_egemm : fp8 QK^T MEGA: grid 256, block owns (bh,qt), loops 4 p-segments
//            (NT=32 continuous K-tiles, fill paid once). Pt + partial Z.
//  k_zfinal: RZ = 1/sum(16 slices)
//  k_vt    : Vb -> Vt [bh][f][1024] bf16 with 1/Z folded
//  k_pv    : bf16 PV MEGA: grid 256, block owns (bh,qt), loops 2 f-segments
//            (NT=32 continuous). float4 out stores.
// Mega cores: per-segment epilogue after tail tile; boundary = stage(next seg
// tile0) + vmcnt(0) + barrier (stores are older than boundary stages -> the
// single counted drain is safe). Fill/drain amortized 2-4x vs split grids.

typedef unsigned char u8;
typedef unsigned short u16;
typedef unsigned int u32;
typedef unsigned long long u64;
typedef __attribute__((ext_vector_type(8))) short bfx8;
typedef __attribute__((ext_vector_type(4))) float fx4;
typedef __attribute__((ext_vector_type(2))) long lx2;

constexpr float KC1 = 1.4426950408889634f / 22.627416997969522f; // log2(e)/sqrt(512)
constexpr float KC8 = KC1 / 256.0f;
constexpr float S8 = 16.0f;

__device__ __forceinline__ u16 f2bf(float f) {
  u32 u = __builtin_bit_cast(u32, f);
  return (u16)((u + 0x7fffu + ((u >> 16) & 1u)) >> 16);
}
__device__ __forceinline__ float bf2f(u16 v) {
  return __builtin_bit_cast(float, (u32)v << 16);
}
__device__ __forceinline__ fx4 mfma16(bfx8 a, bfx8 b, fx4 c) {
  return __builtin_amdgcn_mfma_f32_16x16x32_bf16(a, b, c, 0, 0, 0);
}
__device__ __forceinline__ fx4 mfma8(long a, long b, fx4 c) {
  return __builtin_amdgcn_mfma_f32_16x16x32_fp8_fp8(a, b, c, 0, 0, 0);
}
typedef __attribute__((address_space(1))) const unsigned int* as1p;
typedef __attribute__((address_space(3))) unsigned int* as3p;
__device__ __forceinline__ void gll16(const void* g, void* l) {
  __builtin_amdgcn_global_load_lds((as1p)g, (as3p)l, 16, 0, 0);
}
#define SB0 __builtin_amdgcn_sched_barrier(0)
#define VMC0 do { asm volatile("s_waitcnt vmcnt(0)" ::: "memory"); SB0; } while (0)

// ---- bf16 16-wave 256x256 core, multi-segment (A fixed-ish, B advances) ----
// LDS (u16 idx): A0=0, A1=16384, B0=32768, B1=49152. NT must be even.
template <bool SWAP, int NSEG, int NT, int LK, int ASEG, int BSEG, typename Epi>
__device__ __forceinline__ void gemmWM(const u16* __restrict__ Ag,
                                       const u16* __restrict__ Bg,
                                       u16* lds, fx4 (&acc)[4][4],
                                       int wv, int lane, Epi&& epi) {
  const int l15 = lane & 15, kg = lane >> 4, l7 = lane & 7;
  const int wr = wv >> 2, wn = wv & 3;
  const int rsub = lane >> 3, csub = (lane & 7) * 8;

  auto stg = [&](const u16* g, int ldsoff, int t) {  // 2 gll16: rows wv*16..+16
#pragma unroll
    for (int i = 0; i < 2; ++i)
      gll16(g + (size_t)(wv * 16 + i * 8 + rsub) * LK + t * 64 + csub,
            lds + ldsoff + (wv * 16 + i * 8) * 64);
  };
  bfx8 af[4], bf[4];
  auto rdA = [&](int kk, int aoff) {
#pragma unroll
    for (int mt = 0; mt < 4; ++mt)
      af[mt] = *(const bfx8*)(lds + aoff + (wr * 64 + mt * 16 + l15) * 64 +
                              (((kk << 2) + kg) ^ l7) * 8);
  };
  auto rdB = [&](int kk, int boff) {
#pragma unroll
    for (int nt = 0; nt < 4; ++nt)
      bf[nt] = *(const bfx8*)(lds + boff + (wn * 64 + nt * 16 + l15) * 64 +
                              (((kk << 2) + kg) ^ l7) * 8);
  };
  auto MM = [&]() {
    __builtin_amdgcn_s_setprio(1);
#pragma unroll
    for (int mt = 0; mt < 4; ++mt)
#pragma unroll
      for (int nt = 0; nt < 4; ++nt) {
        if constexpr (SWAP)
          acc[mt][nt] = mfma16(bf[nt], af[mt], acc[mt][nt]);
        else
          acc[mt][nt] = mfma16(af[mt], bf[nt], acc[mt][nt]);
      }
    __builtin_amdgcn_s_setprio(0);
  };

  stg(Ag, 0, 0); stg(Bg, 32768, 0);
  VMC0;
  __builtin_amdgcn_s_barrier();
  SB0;
#pragma unroll 1
  for (int s = 0; s < NSEG; ++s) {
    const u16* As_ = Ag + (size_t)s * ASEG;
    const u16* Bs_ = Bg + (size_t)s * BSEG;
#pragma unroll 1
    for (int t = 0; t < NT; ++t) {
      const int cA = (t & 1) ? 16384 : 0, cB = (t & 1) ? 49152 : 32768;
      const int nA = (t & 1) ? 0 : 16384, nB = (t & 1) ? 32768 : 49152;
      const bool more = (t + 1 < NT);
      if (more) { stg(As_, nA, t + 1); stg(Bs_, nB, t + 1); }
      rdA(0, cA); rdB(0, cB);
      MM();
      rdA(1, cA); rdB(1, cB);
      MM();
      if (more) {
        VMC0;
        __builtin_amdgcn_s_barrier();
        SB0;
      }
    }
    epi(s);                                  // global stores only; resets acc
    if (s + 1 < NSEG) {                      // boundary: refill buf0 (tile 0)
      stg(Ag + (size_t)(s + 1) * ASEG, 0, 0);
      stg(Bg + (size_t)(s + 1) * BSEG, 32768, 0);
      VMC0;                                  // drains epi stores + stages
      __builtin_amdgcn_s_barrier();
      SB0;
    }
  }
}

// ---- fp8 16-wave 256x256 core, multi-segment (interleaved layout) ----
// LDS (u8 idx): A0=0, A1=16384, B0=32768, B1=49152. NT even.
template <int NSEG, int NT, int LK, int ASEG, int BSEG, typename Epi>
__device__ __forceinline__ void gemmWfM(const u8* __restrict__ Ag,
                                        const u8* __restrict__ Bg,
                                        u8* lds, fx4 (&acc)[4][4],
                                        int wv, int lane, Epi&& epi) {
  const int l15 = lane & 15, kg = lane >> 4;
  const int wr = wv >> 2, wn = wv & 3;
  const int rs4 = lane >> 2, c16 = (lane & 3) * 16;
  const int usw = (kg ^ ((l15 >> 1) & 3)) << 4;

  auto stg = [&](const u8* g, int ldsoff, int t) {
    gll16(g + (size_t)(wv * 16 + rs4) * LK + t * 64 + c16, lds + ldsoff + wv * 1024);
  };
  lx2 af[4], bf[4];
  auto rdA = [&](int aoff) {
#pragma unroll
    for (int mt = 0; mt < 4; ++mt)
      af[mt] = *(const lx2*)(lds + aoff + (wr * 64 + mt * 16 + l15) * 64 + usw);
  };
  auto rdB = [&](int boff) {
#pragma unroll
    for (int nt = 0; nt < 4; ++nt)
      bf[nt] = *(const lx2*)(lds + boff + (wn * 64 + nt * 16 + l15) * 64 + usw);
  };
  auto MM = [&](int kk) {   // SWAP form: B first (rows from B-side)
    __builtin_amdgcn_s_setprio(1);
#pragma unroll
    for (int mt = 0; mt < 4; ++mt)
#pragma unroll
      for (int nt = 0; nt < 4; ++nt)
        acc[mt][nt] = mfma8(kk ? bf[nt].y : bf[nt].x,
                            kk ? af[mt].y : af[mt].x, acc[mt][nt]);
    __builtin_amdgcn_s_setprio(0);
  };

  stg(Ag, 0, 0); stg(Bg, 32768, 0);
  VMC0;
  __builtin_amdgcn_s_barrier();
  SB0;
#pragma unroll 1
  for (int s = 0; s < NSEG; ++s) {
    const u8* As_ = Ag + (size_t)s * ASEG;
    const u8* Bs_ = Bg + (size_t)s * BSEG;
#pragma unroll 1
    for (int t = 0; t < NT; ++t) {
      const int cA = (t & 1) ? 16384 : 0, cB = (t & 1) ? 49152 : 32768;
      const int nA = (t & 1) ? 0 : 16384, nB = (t & 1) ? 32768 : 49152;
      const bool more = (t + 1 < NT);
      if (more) { stg(As_, nA, t + 1); stg(Bs_, nB, t + 1); }
      rdA(cA); rdB(cB);
      MM(0);
      MM(1);
      if (more) {
        VMC0;
        __builtin_amdgcn_s_barrier();
        SB0;
      }
    }
    epi(s);
    if (s + 1 < NSEG) {
      stg(Ag + (size_t)(s + 1) * ASEG, 0, 0);
      stg(Bg + (size_t)(s + 1) * BSEG, 32768, 0);
      VMC0;
      __builtin_amdgcn_s_barrier();
      SB0;
    }
  }
}

// ---------------- W fp32 -> Wall bf16 swizzled ----------------
__global__ __launch_bounds__(256) void k_wconv(const float* __restrict__ Wk,
                                               const float* __restrict__ Wq,
                                               const float* __restrict__ Wv,
                                               u16* __restrict__ Wall) {
  int blk = blockIdx.x;          // 96 = 3 proj * 32
  int pr = blk >> 5;
  const float* src = (pr == 0) ? Wk : ((pr == 1) ? Wq : Wv);
  int oc = (blk & 31) * 8 + (threadIdx.x >> 5);
  int Cc = threadIdx.x & 31;
  const float4* s4 = (const float4*)(src + oc * 256 + Cc * 8);
  float4 a = s4[0], b = s4[1];
  alignas(16) u16 t[8] = {f2bf(a.x), f2bf(a.y), f2bf(a.z), f2bf(a.w),
                          f2bf(b.x), f2bf(b.y), f2bf(b.z), f2bf(b.w)};
  int o = pr * 256 + oc;
  int pos = (Cc & ~7) + ((Cc & 7) ^ (o & 7));
  *(uint4*)(Wall + o * 256 + pos * 8) = *(const uint4*)t;
}

// ---------------- x -> Xbf transpose/convert ----------------
__global__ __launch_bounds__(256) void k_xt(const float* __restrict__ x,
                                            u16* __restrict__ Xbf) {
  __shared__ u16 Xs[128 * 256];
  int b = blockIdx.x >> 7;
  int n0 = (blockIdx.x & 127) * 128;
  int tid = threadIdx.x;
  int ng = tid & 31, cgrp = tid >> 5;
  const float* xb = x + (size_t)b * 4194304 + n0 + ng * 4;
#pragma unroll
  for (int it = 0; it < 4; ++it) {
    int Cc = cgrp + it * 8;
    float4 v[8];
#pragma unroll
    for (int i = 0; i < 8; ++i)
      v[i] = *(const float4*)(xb + (size_t)(Cc * 8 + i) * 16384);
#pragma unroll
    for (int j = 0; j < 4; ++j) {
      int n = ng * 4 + j;
      alignas(16) u16 c8v[8];
#pragma unroll
      for (int i = 0; i < 8; ++i) c8v[i] = f2bf(((const float*)&v[i])[j]);
      int pos = (Cc & ~7) + ((Cc & 7) ^ (n & 7));
      *(uint4*)&Xs[n * 256 + pos * 8] = *(const uint4*)c8v;
    }
  }
  __syncthreads();
  u16* xo = Xbf + (size_t)b * 4194304 + (size_t)n0 * 256;
#pragma unroll
  for (int it = 0; it < 16; ++it) {
    int idx = tid + it * 256;
    int n = idx >> 5, chp = idx & 31;
    uint4 v = *(const uint4*)&Xs[n * 256 + chp * 8];
    *(uint4*)&xo[(size_t)n * 256 + chp * 8] = v;
  }
}

// ---------------- fused 3-projection GEMM (round-13, verified) ----------------
// grid 1536, 1024 thr, 256(o) x 256(n), single segment NT=4.
__global__ __launch_bounds__(1024, 4) void k_proj2(const u16* __restrict__ Xbf,
                                                   const u16* __restrict__ Wall,
                                                   u8* __restrict__ Kb8, u8* __restrict__ Qb8,
                                                   u16* __restrict__ Vb) {
  __shared__ u16 lds[65536];
  int bid = blockIdx.x;
  int vid = (bid & 7) * 192 + (bid >> 3);
  int nidx = vid / 3;
  int otile = vid - nidx * 3;
  int b = nidx >> 6, ntile = nidx & 63;
  int tid = threadIdx.x, lane = tid & 63, wv = tid >> 6;
  int l15 = lane & 15, kg = lane >> 4;
  int wr = wv >> 2, wn = wv & 3;
  const u16* Ag = Wall + otile * 65536;
  const u16* Bg = Xbf + (size_t)b * 4194304 + (size_t)ntile * 65536;
  fx4 acc[4][4];
#pragma unroll
  for (int mt = 0; mt < 4; ++mt)
#pragma unroll
    for (int nt = 0; nt < 4; ++nt) acc[mt][nt] = (fx4)0.0f;

  auto epi = [&](int) {
#pragma unroll
    for (int mt = 0; mt < 4; ++mt) {
      int o = wr * 64 + mt * 16 + l15;   // A-side: carries l15
      int h = o >> 5, d = o & 31;
      int f0 = d * 16 + kg * 4;          // t = kg*4 + j
      if (otile < 2) {
        u8* dst = (otile == 0) ? Kb8 : Qb8;
        size_t bhro = (size_t)(b * 8 + h) * 524288;
        int tk = f0 >> 6, kb = f0 & 63;
        int kkb = kb >> 5, kgl = (kb >> 3) & 3, off = kb & 7;
#pragma unroll
        for (int nt = 0; nt < 4; ++nt) {
          int n = wn * 64 + nt * 16 + kg * 4;
          int p = ntile * 16 + (n >> 4);
          const fx4& a4 = acc[mt][nt];
          u32 w = __builtin_amdgcn_cvt_pk_fp8_f32(a4[0] * S8, a4[1] * S8, 0, false);
          w = __builtin_amdgcn_cvt_pk_fp8_f32(a4[2] * S8, a4[3] * S8, w, true);
          int phys = tk * 64 + ((kgl ^ ((p >> 1) & 3)) << 4) + kkb * 8 + off;
          *(u32*)(dst + bhro + (size_t)p * 512 + phys) = w;
        }
      } else {
        size_t bhro = (size_t)(b * 8 + h) * 524288;
        int f7 = f0 & 7, fc = f0 >> 3;
#pragma unroll
        for (int nt = 0; nt < 4; ++nt) {
          int n = wn * 64 + nt * 16 + kg * 4;
          int p = ntile * 16 + (n >> 4);
          alignas(8) u16 e4[4];
#pragma unroll
          for (int j = 0; j < 4; ++j) e4[j] = f2bf(acc[mt][nt][j]);
          int ch = fc ^ (p & 7);
          *(u64*)(Vb + bhro + (size_t)p * 512 + ch * 8 + f7) = *(const u64*)e4;
        }
      }
    }
  };

  gemmWM<true, 1, 4, 256, 0, 0>(Ag, Bg, lds, acc, wv, lane, epi);
}

// ---------------- fp8 E-GEMM MEGA ----------------
// grid 256 (64 bh x 4 qt), 1024 thr; loops 4 p-segments, NT=32 continuous.
__global__ __launch_bounds__(1024, 4) void k_egemm(const u8* __restrict__ Qb8,
                                                   const u8* __restrict__ Kb8,
                                                   u16* __restrict__ Pt,
                                                   float* __restrict__ Zpart) {
  __shared__ u8 lds[65536];
  int bid = blockIdx.x;
  int vid = (bid & 7) * 32 + (bid >> 3);
  int bh = vid >> 2, qt = vid & 3;
  int q0 = qt * 256;
  int tid = threadIdx.x, lane = tid & 63, wv = tid >> 6;
  int l15 = lane & 15, kg = lane >> 4;
  int wr = wv >> 2, wn = wv & 3;
  const u8* Ag = Qb8 + (size_t)bh * 524288 + (size_t)q0 * 512;
  const u8* Bg = Kb8 + (size_t)bh * 524288;
  size_t pbase = (size_t)bh * 1048576;
  fx4 acc[4][4];
#pragma unroll
  for (int mt = 0; mt < 4; ++mt)
#pragma unroll
    for (int nt = 0; nt < 4; ++nt) acc[mt][nt] = (fx4)0.0f;

  auto epi = [&](int s) {
    int p0 = s * 256;
    float zac[4][4];
#pragma unroll
    for (int nt = 0; nt < 4; ++nt)
#pragma unroll
      for (int j = 0; j < 4; ++j) zac[nt][j] = 0.f;
#pragma unroll
    for (int mt = 0; mt < 4; ++mt) {
      int q = q0 + wr * 64 + mt * 16 + l15;
      size_t qrow = pbase + (size_t)q * 1024;
      int q7 = l15 & 7;
#pragma unroll
      for (int nt = 0; nt < 4; ++nt) {
        int p4 = p0 + wn * 64 + nt * 16 + kg * 4;
        alignas(8) u16 e4[4];
#pragma unroll
        for (int j = 0; j < 4; ++j) {
          float e = exp2f(acc[mt][nt][j] * KC8);
          zac[nt][j] += e;
          e4[j] = f2bf(e);
        }
        int ch = (p4 >> 3) ^ q7;
        *(u64*)(Pt + qrow + ch * 8 + (p4 & 7)) = *(const u64*)e4;
        acc[mt][nt] = (fx4)0.0f;
      }
    }
#pragma unroll
    for (int nt = 0; nt < 4; ++nt)
#pragma unroll
      for (int j = 0; j < 4; ++j) {
        float v = zac[nt][j];
        v += __shfl_xor(v, 1);
        v += __shfl_xor(v, 2);
        v += __shfl_xor(v, 4);
        v += __shfl_xor(v, 8);
        zac[nt][j] = v;
      }
    if (l15 == 0) {
      size_t zb = (size_t)(qt * 4 + wr) * 65536 + (size_t)bh * 1024;
#pragma unroll
      for (int nt = 0; nt < 4; ++nt) {
        int p4 = p0 + wn * 64 + nt * 16 + kg * 4;
        float4 zv;
        zv.x = zac[nt][0]; zv.y = zac[nt][1];
        zv.z = zac[nt][2]; zv.w = zac[nt][3];
        *(float4*)&Zpart[zb + p4] = zv;
      }
    }
  };

  gemmWfM<4, 8, 512, 0, 131072>(Ag, Bg, lds, acc, wv, lane, epi);
}

__global__ __launch_bounds__(256) void k_zfinal(const float* __restrict__ Zpart,
                                                float* __restrict__ RZ) {
  int idx = blockIdx.x * 256 + threadIdx.x; // 65536
  float s = 0.f;
#pragma unroll
  for (int k = 0; k < 16; ++k) s += Zpart[(size_t)k * 65536 + idx];
  RZ[idx] = 1.0f / s;
}

// ---------------- Vb [p][f] -> Vt [f][p] with 1/Z scale ----------------
__global__ __launch_bounds__(256) void k_vt(const u16* __restrict__ Vb,
                                            const float* __restrict__ RZ,
                                            u16* __restrict__ Vt) {
  __shared__ u16 Vl[64 * 512];
  int bh = blockIdx.x >> 4;
  int ptile = blockIdx.x & 15;
  int tid = threadIdx.x;
  const u16* src = Vb + (size_t)bh * 524288 + (size_t)ptile * 32768;
#pragma unroll
  for (int it = 0; it < 16; ++it) {
    int idx = tid + it * 256;
    int pl = idx >> 6, g = idx & 63;
    float rz = RZ[bh * 1024 + ptile * 64 + pl];
    uint4 v = *(const uint4*)&src[(size_t)pl * 512 + g * 8];
    int cf = g ^ (pl & 7);
    u32 w[4] = {v.x, v.y, v.z, v.w};
    alignas(16) u16 c8v[8];
#pragma unroll
    for (int i = 0; i < 4; ++i) {
      c8v[2 * i]     = f2bf(bf2f((u16)w[i]) * rz);
      c8v[2 * i + 1] = f2bf(bf2f((u16)(w[i] >> 16)) * rz);
    }
    *(uint4*)&Vl[pl * 512 + cf * 8] = *(const uint4*)c8v;
  }
  __syncthreads();
  u16* dst = Vt + (size_t)bh * 524288;
#pragma unroll
  for (int it = 0; it < 16; ++it) {
    int f = (tid & 63) + (it & 7) * 64;
    int pc = (tid >> 6) * 2 + (it >> 3);
    int base = pc * 8 * 512 + f;
    u32 x0 = (u32)Vl[base] | ((u32)Vl[base + 512] << 16);
    u32 x1 = (u32)Vl[base + 1024] | ((u32)Vl[base + 1536] << 16);
    u32 x2 = (u32)Vl[base + 2048] | ((u32)Vl[base + 2560] << 16);
    u32 x3 = (u32)Vl[base + 3072] | ((u32)Vl[base + 3584] << 16);
    uint4 pk; pk.x = x0; pk.y = x1; pk.z = x2; pk.w = x3;
    int col = ptile * 8 + (pc ^ (f & 7));
    *(uint4*)&dst[(size_t)f * 1024 + col * 8] = pk;
  }
}

// ---------------- PV-GEMM MEGA -> out ----------------
// grid 256 (64 bh x 4 qt), 1024 thr; loops 2 f-segments, NT=32 continuous.
__global__ __launch_bounds__(1024, 4) void k_pv(const u16* __restrict__ Pt,
                                                const u16* __restrict__ Vt,
                                                float* __restrict__ out) {
  __shared__ u16 lds[65536];
  int bid = blockIdx.x;
  int vid = (bid & 7) * 32 + (bid >> 3);
  int bh = vid >> 2, qt = vid & 3;
  int q0 = qt * 256;
  int tid = threadIdx.x, lane = tid & 63, wv = tid >> 6;
  int l15 = lane & 15, kg = lane >> 4;
  int wr = wv >> 2, wn = wv & 3;
  const u16* Ag = Pt + (size_t)bh * 1048576 + (size_t)q0 * 1024;
  const u16* Bg = Vt + (size_t)bh * 524288;
  fx4 acc[4][4];
#pragma unroll
  for (int mt = 0; mt < 4; ++mt)
#pragma unroll
    for (int nt = 0; nt < 4; ++nt) acc[mt][nt] = (fx4)0.0f;

  auto epi = [&](int s) {
    int f0 = s * 256;
#pragma unroll
    for (int mt = 0; mt < 4; ++mt) {
      int q = q0 + wr * 64 + mt * 16 + l15;
#pragma unroll
      for (int nt = 0; nt < 4; ++nt) {
        int fb = f0 + wn * 64 + nt * 16 + kg * 4;  // t = kg*4+j
        int d = fb >> 4, t0 = fb & 15;
        float4 v;
        v.x = acc[mt][nt][0];
        v.y = acc[mt][nt][1];
        v.z = acc[mt][nt][2];
        v.w = acc[mt][nt][3];
        *(float4*)&out[(size_t)(bh * 32 + d) * 16384 + (size_t)q * 16 + t0] = v;
        acc[mt][nt] = (fx4)0.0f;
      }
    }
  };

  gemmWM<true, 2, 16, 1024, 0, 262144>(Ag, Bg, lds, acc, wv, lane, epi);
}

extern "C" void kernel_launch(void* const* d_in, const int* in_sizes, int n_in,
                              void* d_out, int out_size, void* d_ws, size_t ws_size,
                              hipStream_t stream) {
  (void)in_sizes; (void)n_in; (void)out_size; (void)ws_size;
  const float* x  = (const float*)d_in[0];
  const float* Wk = (const float*)d_in[1];
  const float* Wq = (const float*)d_in[2];
  const float* Wv = (const float*)d_in[3];
  float* out = (float*)d_out;

  u8* base = (u8*)d_ws;
  u8*  Kb8 = base;                          // [  0, 32) MiB [64 bh][1024 p][512B]
  u8*  Qb8 = base + 33554432;               // [ 32, 64)
  u16* Vb  = (u16*)(base + 67108864);       // [ 64,128) MiB bf16 [bh][p][512]
  u16* Xbf = (u16*)(base + 134217728);      // [128,192) MiB bf16 [b][n][c]
  u16* Pt  = Xbf;                           // [128,256) MiB (overlays dead Xbf)
  u16* Vt  = (u16*)(base + 268435456);      // [256,320) MiB bf16 [bh][f][1024]
  float* Zpart = (float*)(base + 335544320);// [16][64][1024]
  float* RZ = Zpart + 1048576;              // [64][1024]
  u16* Wall = (u16*)(RZ + 65536);           // [768][256]

  k_wconv<<<96, 256, 0, stream>>>(Wk, Wq, Wv, Wall);
  k_xt<<<1024, 256, 0, stream>>>(x, Xbf);
  k_proj2<<<1536, 1024, 0, stream>>>(Xbf, Wall, Kb8, Qb8, Vb);
  k_egemm<<<256, 1024, 0, stream>>>(Qb8, Kb8, Pt, Zpart);
  k_zfinal<<<256, 256, 0, stream>>>(Zpart, RZ);
  k_vt<<<1024, 256, 0, stream>>>(Vb, RZ, Vt);
  k_pv<<<256, 1024, 0, stream>>>(Pt, Vt, out);
}

// Round 15
// 312.752 us; speedup vs baseline: 1.0641x; 1.0641x over previous
//
#include <hip/hip_runtime.h>

// MultiHeadAttention: B=8, C=256, H=8, D=32, T=16, P=1024, F=D*T=512
// Best-of-per-kernel hybrid (rounds 12+13), zfinal fused into vt:
//  k_wconv : W fp32 -> Wall[768][256] bf16 (chunk-swizzled by o&7)
//  k_xt    : x fp32 [b][c][n] -> Xbf [b][n][c] bf16 (chunk-swizzled by n&7)
//  k_proj2 : [r13] 1024-thr GEMM. K,Q -> fp8e4m3 x16 INTERLEAVED layout; V bf16.
//  k_egemm : [r13] 1024-thr fp8 QK^T, conflict-free b128 LDS reads,
//            Pt=bf16(exp2(E*KC8)) + partial Z (16 slices).
//  k_vt    : Vb -> Vt [bh][f][1024] bf16 with 1/Z folded; Z summed inline
//            from the 16 Zpart slices (zfinal fused).
//  k_pv    : [r12] 512-thr bf16 8-phase gemm8, SWAP, float4 out stores.

typedef unsigned char u8;
typedef unsigned short u16;
typedef unsigned int u32;
typedef unsigned long long u64;
typedef __attribute__((ext_vector_type(8))) short bfx8;
typedef __attribute__((ext_vector_type(4))) float fx4;
typedef __attribute__((ext_vector_type(2))) long lx2;

constexpr float KC1 = 1.4426950408889634f / 22.627416997969522f; // log2(e)/sqrt(512)
constexpr float KC8 = KC1 / 256.0f;
constexpr float S8 = 16.0f;

__device__ __forceinline__ u16 f2bf(float f) {
  u32 u = __builtin_bit_cast(u32, f);
  return (u16)((u + 0x7fffu + ((u >> 16) & 1u)) >> 16);
}
__device__ __forceinline__ float bf2f(u16 v) {
  return __builtin_bit_cast(float, (u32)v << 16);
}
__device__ __forceinline__ fx4 mfma16(bfx8 a, bfx8 b, fx4 c) {
  return __builtin_amdgcn_mfma_f32_16x16x32_bf16(a, b, c, 0, 0, 0);
}
__device__ __forceinline__ fx4 mfma8(long a, long b, fx4 c) {
  return __builtin_amdgcn_mfma_f32_16x16x32_fp8_fp8(a, b, c, 0, 0, 0);
}
typedef __attribute__((address_space(1))) const unsigned int* as1p;
typedef __attribute__((address_space(3))) unsigned int* as3p;
__device__ __forceinline__ void gll16(const void* g, void* l) {
  __builtin_amdgcn_global_load_lds((as1p)g, (as3p)l, 16, 0, 0);
}
#define SB0 __builtin_amdgcn_sched_barrier(0)
#define VMC0 do { asm volatile("s_waitcnt vmcnt(0)" ::: "memory"); SB0; } while (0)
#define VMC4 do { asm volatile("s_waitcnt vmcnt(4)" ::: "memory"); SB0; } while (0)
__device__ __forceinline__ void midbar_() { __builtin_amdgcn_s_barrier(); }
__device__ __forceinline__ void pend_() {
  __builtin_amdgcn_s_barrier();
  SB0;
}

// ---- [r13] bf16 16-wave 256x256 core, 1 gate per K-tile ----
template <bool SWAP, int NT, int LK>
__device__ __forceinline__ void gemmW(const u16* __restrict__ Ag,
                                      const u16* __restrict__ Bg,
                                      u16* lds, fx4 (&acc)[4][4],
                                      int wv, int lane) {
  const int l15 = lane & 15, kg = lane >> 4, l7 = lane & 7;
  const int wr = wv >> 2, wn = wv & 3;
  const int rsub = lane >> 3, csub = (lane & 7) * 8;

  auto stg = [&](const u16* g, int ldsoff, int t) {
#pragma unroll
    for (int i = 0; i < 2; ++i)
      gll16(g + (size_t)(wv * 16 + i * 8 + rsub) * LK + t * 64 + csub,
            lds + ldsoff + (wv * 16 + i * 8) * 64);
  };
  bfx8 af[4], bf[4];
  auto rdA = [&](int kk, int aoff) {
#pragma unroll
    for (int mt = 0; mt < 4; ++mt)
      af[mt] = *(const bfx8*)(lds + aoff + (wr * 64 + mt * 16 + l15) * 64 +
                              (((kk << 2) + kg) ^ l7) * 8);
  };
  auto rdB = [&](int kk, int boff) {
#pragma unroll
    for (int nt = 0; nt < 4; ++nt)
      bf[nt] = *(const bfx8*)(lds + boff + (wn * 64 + nt * 16 + l15) * 64 +
                              (((kk << 2) + kg) ^ l7) * 8);
  };
  auto MM = [&]() {
    __builtin_amdgcn_s_setprio(1);
#pragma unroll
    for (int mt = 0; mt < 4; ++mt)
#pragma unroll
      for (int nt = 0; nt < 4; ++nt) {
        if constexpr (SWAP)
          acc[mt][nt] = mfma16(bf[nt], af[mt], acc[mt][nt]);
        else
          acc[mt][nt] = mfma16(af[mt], bf[nt], acc[mt][nt]);
      }
    __builtin_amdgcn_s_setprio(0);
  };

  stg(Ag, 0, 0); stg(Bg, 32768, 0);
  VMC0;
  __builtin_amdgcn_s_barrier();
  SB0;
#pragma unroll 1
  for (int t = 0; t < NT; ++t) {
    const int cA = (t & 1) ? 16384 : 0, cB = (t & 1) ? 49152 : 32768;
    const int nA = (t & 1) ? 0 : 16384, nB = (t & 1) ? 32768 : 49152;
    const bool more = (t + 1 < NT);
    if (more) { stg(Ag, nA, t + 1); stg(Bg, nB, t + 1); }
    rdA(0, cA); rdB(0, cB);
    MM();
    rdA(1, cA); rdB(1, cB);
    MM();
    if (more) {
      VMC0;
      __builtin_amdgcn_s_barrier();
      SB0;
    }
  }
}

// ---- [r13] fp8 16-wave 256x256 core (interleaved layout, b128 reads) ----
template <int NT, int LK>
__device__ __forceinline__ void gemmWf(const u8* __restrict__ Ag,
                                       const u8* __restrict__ Bg,
                                       u8* lds, fx4 (&acc)[4][4],
                                       int wv, int lane) {
  const int l15 = lane & 15, kg = lane >> 4;
  const int wr = wv >> 2, wn = wv & 3;
  const int rs4 = lane >> 2, c16 = (lane & 3) * 16;
  const int usw = (kg ^ ((l15 >> 1) & 3)) << 4;

  auto stg = [&](const u8* g, int ldsoff, int t) {
    gll16(g + (size_t)(wv * 16 + rs4) * LK + t * 64 + c16, lds + ldsoff + wv * 1024);
  };
  lx2 af[4], bf[4];
  auto rdA = [&](int aoff) {
#pragma unroll
    for (int mt = 0; mt < 4; ++mt)
      af[mt] = *(const lx2*)(lds + aoff + (wr * 64 + mt * 16 + l15) * 64 + usw);
  };
  auto rdB = [&](int boff) {
#pragma unroll
    for (int nt = 0; nt < 4; ++nt)
      bf[nt] = *(const lx2*)(lds + boff + (wn * 64 + nt * 16 + l15) * 64 + usw);
  };
  auto MM = [&](int kk) {   // SWAP form: B first (rows from B-side)
    __builtin_amdgcn_s_setprio(1);
#pragma unroll
    for (int mt = 0; mt < 4; ++mt)
#pragma unroll
      for (int nt = 0; nt < 4; ++nt)
        acc[mt][nt] = mfma8(kk ? bf[nt].y : bf[nt].x,
                            kk ? af[mt].y : af[mt].x, acc[mt][nt]);
    __builtin_amdgcn_s_setprio(0);
  };

  stg(Ag, 0, 0); stg(Bg, 32768, 0);
  VMC0;
  __builtin_amdgcn_s_barrier();
  SB0;
#pragma unroll 1
  for (int t = 0; t < NT; ++t) {
    const int cA = (t & 1) ? 16384 : 0, cB = (t & 1) ? 49152 : 32768;
    const int nA = (t & 1) ? 0 : 16384, nB = (t & 1) ? 32768 : 49152;
    const bool more = (t + 1 < NT);
    if (more) { stg(Ag, nA, t + 1); stg(Bg, nB, t + 1); }
    rdA(cA); rdB(cB);
    MM(0);
    MM(1);
    if (more) {
      VMC0;
      __builtin_amdgcn_s_barrier();
      SB0;
    }
  }
}

// ---- [r12] bf16 8-wave 8-phase 256x256 core ----
template <bool SWAP, int NT, int LK>
__device__ __forceinline__ void gemm8(const u16* __restrict__ Ag,
                                      const u16* __restrict__ Bg,
                                      u16* lds, fx4 (&acc)[2][4][2][2],
                                      int wv, int lane) {
  const int l15 = lane & 15, kg = lane >> 4, l7 = lane & 7;
  const int wr = wv >> 2, wn = wv & 3;
  const int rsub = lane >> 3, csub = (lane & 7) * 8;
  constexpr int A0 = 0, A1 = 16384, B0 = 32768, B1 = 49152;
  bfx8 af[4][2], bf[2][2][2];

  auto stg = [&](const u16* g, int ldsoff, int tile, int half) {
    const u16* gp = g + (size_t)(half * 128 + wv * 16 + rsub) * LK + tile * 64 + csub;
    u16* lp = lds + ldsoff + half * 8192 + wv * 1024;
    gll16(gp, lp);
    gll16(gp + (size_t)8 * LK, lp + 512);
  };
  auto LA = [&](int boff, int mh) {
    const u16* base = lds + boff + mh * 8192 + wr * 4096;
#pragma unroll
    for (int mt = 0; mt < 4; ++mt)
#pragma unroll
      for (int kk = 0; kk < 2; ++kk)
        af[mt][kk] = *(const bfx8*)(base + (mt * 16 + l15) * 64 + (((kk << 2) + kg) ^ l7) * 8);
  };
  auto LB = [&](int boff, int nh) {
    const u16* base = lds + boff + nh * 8192 + wn * 2048;
#pragma unroll
    for (int nt = 0; nt < 2; ++nt)
#pragma unroll
      for (int kk = 0; kk < 2; ++kk)
        bf[nh][nt][kk] = *(const bfx8*)(base + (nt * 16 + l15) * 64 + (((kk << 2) + kg) ^ l7) * 8);
  };
  auto MM = [&](int mh, int nh) {
    __builtin_amdgcn_s_setprio(1);
#pragma unroll
    for (int mt = 0; mt < 4; ++mt)
#pragma unroll
      for (int nt = 0; nt < 2; ++nt)
#pragma unroll
        for (int kk = 0; kk < 2; ++kk) {
          if constexpr (SWAP)
            acc[mh][mt][nh][nt] = mfma16(bf[nh][nt][kk], af[mt][kk], acc[mh][mt][nh][nt]);
          else
            acc[mh][mt][nh][nt] = mfma16(af[mt][kk], bf[nh][nt][kk], acc[mh][mt][nh][nt]);
        }
    __builtin_amdgcn_s_setprio(0);
  };

  stg(Ag, A0, 0, 0); stg(Ag, A0, 0, 1);
  stg(Bg, B0, 0, 0); stg(Bg, B0, 0, 1);
  stg(Ag, A1, 1, 0); stg(Bg, B1, 1, 1);
  VMC4;
  pend_();

  constexpr int NI = NT / 2;
#pragma unroll 1
  for (int i = 0; i < NI; ++i) {
    const int t = 2 * i;
    const bool more = (i + 1 < NI);
    LA(A0, 0); LB(B0, 0);
    stg(Ag, A1, t + 1, 1);
    midbar_(); MM(0, 0); pend_();
    LB(B0, 1);
    stg(Bg, B1, t + 1, 0);
    midbar_(); MM(0, 1); pend_();
    LA(A0, 1);
    if (more) stg(Ag, A0, t + 2, 0);
    midbar_(); MM(1, 1); pend_();
    if (more) stg(Bg, B0, t + 2, 1);
    midbar_(); MM(1, 0);
    if (more) { VMC4; } else { VMC0; }
    pend_();
    LA(A1, 0); LB(B1, 0);
    if (more) stg(Ag, A0, t + 2, 1);
    midbar_(); MM(0, 0); pend_();
    LB(B1, 1);
    if (more) stg(Bg, B0, t + 2, 0);
    midbar_(); MM(0, 1); pend_();
    LA(A1, 1);
    if (more) stg(Ag, A1, t + 3, 0);
    midbar_(); MM(1, 1); pend_();
    if (more) stg(Bg, B1, t + 3, 1);
    midbar_(); MM(1, 0);
    if (more) { VMC4; }
    pend_();
  }
}

// ---------------- W fp32 -> Wall bf16 swizzled ----------------
__global__ __launch_bounds__(256) void k_wconv(const float* __restrict__ Wk,
                                               const float* __restrict__ Wq,
                                               const float* __restrict__ Wv,
                                               u16* __restrict__ Wall) {
  int blk = blockIdx.x;          // 96 = 3 proj * 32
  int pr = blk >> 5;
  const float* src = (pr == 0) ? Wk : ((pr == 1) ? Wq : Wv);
  int oc = (blk & 31) * 8 + (threadIdx.x >> 5);
  int Cc = threadIdx.x & 31;
  const float4* s4 = (const float4*)(src + oc * 256 + Cc * 8);
  float4 a = s4[0], b = s4[1];
  alignas(16) u16 t[8] = {f2bf(a.x), f2bf(a.y), f2bf(a.z), f2bf(a.w),
                          f2bf(b.x), f2bf(b.y), f2bf(b.z), f2bf(b.w)};
  int o = pr * 256 + oc;
  int pos = (Cc & ~7) + ((Cc & 7) ^ (o & 7));
  *(uint4*)(Wall + o * 256 + pos * 8) = *(const uint4*)t;
}

// ---------------- x -> Xbf transpose/convert ----------------
__global__ __launch_bounds__(256) void k_xt(const float* __restrict__ x,
                                            u16* __restrict__ Xbf) {
  __shared__ u16 Xs[128 * 256];
  int b = blockIdx.x >> 7;
  int n0 = (blockIdx.x & 127) * 128;
  int tid = threadIdx.x;
  int ng = tid & 31, cgrp = tid >> 5;
  const float* xb = x + (size_t)b * 4194304 + n0 + ng * 4;
#pragma unroll
  for (int it = 0; it < 4; ++it) {
    int Cc = cgrp + it * 8;
    float4 v[8];
#pragma unroll
    for (int i = 0; i < 8; ++i)
      v[i] = *(const float4*)(xb + (size_t)(Cc * 8 + i) * 16384);
#pragma unroll
    for (int j = 0; j < 4; ++j) {
      int n = ng * 4 + j;
      alignas(16) u16 c8v[8];
#pragma unroll
      for (int i = 0; i < 8; ++i) c8v[i] = f2bf(((const float*)&v[i])[j]);
      int pos = (Cc & ~7) + ((Cc & 7) ^ (n & 7));
      *(uint4*)&Xs[n * 256 + pos * 8] = *(const uint4*)c8v;
    }
  }
  __syncthreads();
  u16* xo = Xbf + (size_t)b * 4194304 + (size_t)n0 * 256;
#pragma unroll
  for (int it = 0; it < 16; ++it) {
    int idx = tid + it * 256;
    int n = idx >> 5, chp = idx & 31;
    uint4 v = *(const uint4*)&Xs[n * 256 + chp * 8];
    *(uint4*)&xo[(size_t)n * 256 + chp * 8] = v;
  }
}

// ---------------- [r13] fused 3-projection GEMM ----------------
// grid 1536, 1024 thr, 256(o) x 256(n), NT=4. SWAP core.
__global__ __launch_bounds__(1024, 4) void k_proj2(const u16* __restrict__ Xbf,
                                                   const u16* __restrict__ Wall,
                                                   u8* __restrict__ Kb8, u8* __restrict__ Qb8,
                                                   u16* __restrict__ Vb) {
  __shared__ u16 lds[65536];
  int bid = blockIdx.x;
  int vid = (bid & 7) * 192 + (bid >> 3);
  int nidx = vid / 3;
  int otile = vid - nidx * 3;
  int b = nidx >> 6, ntile = nidx & 63;
  int tid = threadIdx.x, lane = tid & 63, wv = tid >> 6;
  int l15 = lane & 15, kg = lane >> 4;
  int wr = wv >> 2, wn = wv & 3;
  const u16* Ag = Wall + otile * 65536;
  const u16* Bg = Xbf + (size_t)b * 4194304 + (size_t)ntile * 65536;
  fx4 acc[4][4];
#pragma unroll
  for (int mt = 0; mt < 4; ++mt)
#pragma unroll
    for (int nt = 0; nt < 4; ++nt) acc[mt][nt] = (fx4)0.0f;

  gemmW<true, 4, 256>(Ag, Bg, lds, acc, wv, lane);

#pragma unroll
  for (int mt = 0; mt < 4; ++mt) {
    int o = wr * 64 + mt * 16 + l15;   // A-side: carries l15
    int h = o >> 5, d = o & 31;
    int f0 = d * 16 + kg * 4;          // t = kg*4 + j
    if (otile < 2) {
      u8* dst = (otile == 0) ? Kb8 : Qb8;
      size_t bhro = (size_t)(b * 8 + h) * 524288;
      int tk = f0 >> 6, kb = f0 & 63;
      int kkb = kb >> 5, kgl = (kb >> 3) & 3, off = kb & 7;
#pragma unroll
      for (int nt = 0; nt < 4; ++nt) {
        int n = wn * 64 + nt * 16 + kg * 4;
        int p = ntile * 16 + (n >> 4);
        const fx4& a4 = acc[mt][nt];
        u32 w = __builtin_amdgcn_cvt_pk_fp8_f32(a4[0] * S8, a4[1] * S8, 0, false);
        w = __builtin_amdgcn_cvt_pk_fp8_f32(a4[2] * S8, a4[3] * S8, w, true);
        int phys = tk * 64 + ((kgl ^ ((p >> 1) & 3)) << 4) + kkb * 8 + off;
        *(u32*)(dst + bhro + (size_t)p * 512 + phys) = w;
      }
    } else {
      size_t bhro = (size_t)(b * 8 + h) * 524288;
      int f7 = f0 & 7, fc = f0 >> 3;
#pragma unroll
      for (int nt = 0; nt < 4; ++nt) {
        int n = wn * 64 + nt * 16 + kg * 4;
        int p = ntile * 16 + (n >> 4);
        alignas(8) u16 e4[4];
#pragma unroll
        for (int j = 0; j < 4; ++j) e4[j] = f2bf(acc[mt][nt][j]);
        int ch = fc ^ (p & 7);
        *(u64*)(Vb + bhro + (size_t)p * 512 + ch * 8 + f7) = *(const u64*)e4;
      }
    }
  }
}

// ---------------- [r13] fp8 E-GEMM + exp2 -> Pt, partial Z ----------------
// grid 1024 (bh x 4 qt x 4 pt), 1024 thr, 256x256, NT=8, 64 KiB LDS.
__global__ __launch_bounds__(1024, 4) void k_egemm(const u8* __restrict__ Qb8,
                                                   const u8* __restrict__ Kb8,
                                                   u16* __restrict__ Pt,
                                                   float* __restrict__ Zpart) {
  __shared__ u8 lds[65536];
  int bid = blockIdx.x;
  int vid = (bid & 7) * 128 + (bid >> 3);
  int bh = vid >> 4, qt = (vid >> 2) & 3, pt = vid & 3;
  int q0 = qt * 256, p0 = pt * 256;
  int tid = threadIdx.x, lane = tid & 63, wv = tid >> 6;
  int l15 = lane & 15, kg = lane >> 4;
  int wr = wv >> 2, wn = wv & 3;
  const u8* Ag = Qb8 + (size_t)bh * 524288 + (size_t)q0 * 512;
  const u8* Bg = Kb8 + (size_t)bh * 524288 + (size_t)p0 * 512;
  fx4 acc[4][4];
#pragma unroll
  for (int mt = 0; mt < 4; ++mt)
#pragma unroll
    for (int nt = 0; nt < 4; ++nt) acc[mt][nt] = (fx4)0.0f;

  gemmWf<8, 512>(Ag, Bg, lds, acc, wv, lane);

  size_t pbase = (size_t)bh * 1048576;
  float zac[4][4];
#pragma unroll
  for (int nt = 0; nt < 4; ++nt)
#pragma unroll
    for (int j = 0; j < 4; ++j) zac[nt][j] = 0.f;
#pragma unroll
  for (int mt = 0; mt < 4; ++mt) {
    int q = q0 + wr * 64 + mt * 16 + l15;
    size_t qrow = pbase + (size_t)q * 1024;
    int q7 = l15 & 7;
#pragma unroll
    for (int nt = 0; nt < 4; ++nt) {
      int p4 = p0 + wn * 64 + nt * 16 + kg * 4;
      alignas(8) u16 e4[4];
#pragma unroll
      for (int j = 0; j < 4; ++j) {
        float e = exp2f(acc[mt][nt][j] * KC8);
        zac[nt][j] += e;
        e4[j] = f2bf(e);
      }
      int ch = (p4 >> 3) ^ q7;
      *(u64*)(Pt + qrow + ch * 8 + (p4 & 7)) = *(const u64*)e4;
    }
  }
#pragma unroll
  for (int nt = 0; nt < 4; ++nt)
#pragma unroll
    for (int j = 0; j < 4; ++j) {
      float v = zac[nt][j];
      v += __shfl_xor(v, 1);
      v += __shfl_xor(v, 2);
      v += __shfl_xor(v, 4);
      v += __shfl_xor(v, 8);
      zac[nt][j] = v;
    }
  if (l15 == 0) {
    size_t zb = (size_t)(qt * 4 + wr) * 65536 + (size_t)bh * 1024;
#pragma unroll
    for (int nt = 0; nt < 4; ++nt) {
      int p4 = p0 + wn * 64 + nt * 16 + kg * 4;
      float4 zv;
      zv.x = zac[nt][0]; zv.y = zac[nt][1];
      zv.z = zac[nt][2]; zv.w = zac[nt][3];
      *(float4*)&Zpart[zb + p4] = zv;
    }
  }
}

// ---------------- Vb -> Vt with 1/Z folded; Z summed inline ----------------
__global__ __launch_bounds__(256) void k_vt(const u16* __restrict__ Vb,
                                            const float* __restrict__ Zpart,
                                            u16* __restrict__ Vt) {
  __shared__ u16 Vl[64 * 512];
  __shared__ float rzs[64];
  int bh = blockIdx.x >> 4;
  int ptile = blockIdx.x & 15;
  int tid = threadIdx.x;
  if (tid < 64) {
    float s = 0.f;
#pragma unroll
    for (int k = 0; k < 16; ++k)
      s += Zpart[(size_t)k * 65536 + bh * 1024 + ptile * 64 + tid];
    rzs[tid] = 1.0f / s;
  }
  __syncthreads();
  const u16* src = Vb + (size_t)bh * 524288 + (size_t)ptile * 32768;
#pragma unroll
  for (int it = 0; it < 16; ++it) {
    int idx = tid + it * 256;
    int pl = idx >> 6, g = idx & 63;
    float rz = rzs[pl];
    uint4 v = *(const uint4*)&src[(size_t)pl * 512 + g * 8];
    int cf = g ^ (pl & 7);
    u32 w[4] = {v.x, v.y, v.z, v.w};
    alignas(16) u16 c8v[8];
#pragma unroll
    for (int i = 0; i < 4; ++i) {
      c8v[2 * i]     = f2bf(bf2f((u16)w[i]) * rz);
      c8v[2 * i + 1] = f2bf(bf2f((u16)(w[i] >> 16)) * rz);
    }
    *(uint4*)&Vl[pl * 512 + cf * 8] = *(const uint4*)c8v;
  }
  __syncthreads();
  u16* dst = Vt + (size_t)bh * 524288;
#pragma unroll
  for (int it = 0; it < 16; ++it) {
    int f = (tid & 63) + (it & 7) * 64;
    int pc = (tid >> 6) * 2 + (it >> 3);
    int base = pc * 8 * 512 + f;
    u32 x0 = (u32)Vl[base] | ((u32)Vl[base + 512] << 16);
    u32 x1 = (u32)Vl[base + 1024] | ((u32)Vl[base + 1536] << 16);
    u32 x2 = (u32)Vl[base + 2048] | ((u32)Vl[base + 2560] << 16);
    u32 x3 = (u32)Vl[base + 3072] | ((u32)Vl[base + 3584] << 16);
    uint4 pk; pk.x = x0; pk.y = x1; pk.z = x2; pk.w = x3;
    int col = ptile * 8 + (pc ^ (f & 7));
    *(uint4*)&dst[(size_t)f * 1024 + col * 8] = pk;
  }
}

// ---------------- [r12] PV-GEMM -> out (bf16, SWAP, float4 stores) ----------------
// grid 512 (bh x 8 tiles), 512 thr, 256x256, NT=16.
__global__ __launch_bounds__(512) void k_pv(const u16* __restrict__ Pt,
                                            const u16* __restrict__ Vt,
                                            float* __restrict__ out) {
  __shared__ u16 lds[65536];
  int bid = blockIdx.x;
  int vid = (bid & 7) * 64 + (bid >> 3);
  int bh = vid >> 3, tile = vid & 7;
  int q0 = (tile >> 1) * 256, f0 = (tile & 1) * 256;
  int tid = threadIdx.x, lane = tid & 63, wv = tid >> 6;
  int l15 = lane & 15, kg = lane >> 4;
  int wr = wv >> 2, wn = wv & 3;
  const u16* Ag = Pt + (size_t)bh * 1048576 + (size_t)q0 * 1024;
  const u16* Bg = Vt + (size_t)bh * 524288 + (size_t)f0 * 1024;
  fx4 acc[2][4][2][2];
#pragma unroll
  for (int mh = 0; mh < 2; ++mh)
#pragma unroll
    for (int mt = 0; mt < 4; ++mt)
#pragma unroll
      for (int nh = 0; nh < 2; ++nh)
#pragma unroll
        for (int nt = 0; nt < 2; ++nt) acc[mh][mt][nh][nt] = (fx4)0.0f;

  gemm8<true, 16, 1024>(Ag, Bg, lds, acc, wv, lane);

#pragma unroll
  for (int mh = 0; mh < 2; ++mh)
#pragma unroll
    for (int mt = 0; mt < 4; ++mt) {
      int q = q0 + mh * 128 + wr * 64 + mt * 16 + l15;
#pragma unroll
      for (int nh = 0; nh < 2; ++nh)
#pragma unroll
        for (int nt = 0; nt < 2; ++nt) {
          int fb = f0 + nh * 128 + wn * 32 + nt * 16 + kg * 4; // t = kg*4+j
          int d = fb >> 4, t0 = fb & 15;
          float4 v;
          v.x = acc[mh][mt][nh][nt][0];
          v.y = acc[mh][mt][nh][nt][1];
          v.z = acc[mh][mt][nh][nt][2];
          v.w = acc[mh][mt][nh][nt][3];
          *(float4*)&out[(size_t)(bh * 32 + d) * 16384 + (size_t)q * 16 + t0] = v;
        }
    }
}

extern "C" void kernel_launch(void* const* d_in, const int* in_sizes, int n_in,
                              void* d_out, int out_size, void* d_ws, size_t ws_size,
                              hipStream_t stream) {
  (void)in_sizes; (void)n_in; (void)out_size; (void)ws_size;
  const float* x  = (const float*)d_in[0];
  const float* Wk = (const float*)d_in[1];
  const float* Wq = (const float*)d_in[2];
  const float* Wv = (const float*)d_in[3];
  float* out = (float*)d_out;

  u8* base = (u8*)d_ws;
  u8*  Kb8 = base;                          // [  0, 32) MiB [64 bh][1024 p][512B]
  u8*  Qb8 = base + 33554432;               // [ 32, 64)
  u16* Vb  = (u16*)(base + 67108864);       // [ 64,128) MiB bf16 [bh][p][512]
  u16* Xbf = (u16*)(base + 134217728);      // [128,192) MiB bf16 [b][n][c]
  u16* Pt  = Xbf;                           // [128,256) MiB (overlays dead Xbf)
  u16* Vt  = (u16*)(base + 268435456);      // [256,320) MiB bf16 [bh][f][1024]
  float* Zpart = (float*)(base + 335544320);// [16][64][1024]
  float* RZ = Zpart + 1048576;              // (unused; kept for layout)
  u16* Wall = (u16*)(RZ + 65536);           // [768][256]

  k_wconv<<<96, 256, 0, stream>>>(Wk, Wq, Wv, Wall);
  k_xt<<<1024, 256, 0, stream>>>(x, Xbf);
  k_proj2<<<1536, 1024, 0, stream>>>(Xbf, Wall, Kb8, Qb8, Vb);
  k_egemm<<<1024, 1024, 0, stream>>>(Qb8, Kb8, Pt, Zpart);
  k_vt<<<1024, 256, 0, stream>>>(Vb, Zpart, Vt);
  k_pv<<<512, 512, 0, stream>>>(Pt, Vt, out);
}